// Round 1
// baseline (375.911 us; speedup 1.0000x reference)
//
#include <hip/hip_runtime.h>
#include <hip/hip_bf16.h>

// ---------------------------------------------------------------------------
// MonotonicAlignmentSearch: B=2, TT=128, TA=512, H=1024, fp32 baseline.
//
// Pipeline:
//   tp[256][1024]  = text  @ W1[:H]   + b1          (GEMM, split-k=8 + reduce)
//   ap[1024][1024] = audio @ W1[H:]                 (GEMM, split-k=2 + reduce)
//   xT[1024][256]  = transpose(text)                ([i][bt] layout for conv)
//   y1 = relu(conv1(xT)) (implicit-im2col GEMM k=3072, split-k=8; reduce adds
//        bias, relu, GN stats via atomics) ; x1n = GN(y1)
//   y2 = relu(conv2(x1n)) ; x2n = GN(y2)
//   durations = softplus(conv3(x2n))                -> d_out + 131072
//   logits[b,t,a] = sum_h relu(tp+ap)*w2 + b2 - 0.1|a-4t|   (LDS-tiled)
//   alignment = softmax_a(logits)                   -> d_out[0..131071]
// ---------------------------------------------------------------------------

#define H_DIM 1024
#define BT    256      // B*TT
#define TA_N  512
#define EPSV  1e-5f

#define TILE_M 128
#define TILE_N 64
#define BK     16

// ws offsets (floats)
#define OFF_TP     0u          // 262144
#define OFF_AP     262144u     // 1048576
#define OFF_XT     1310720u    // 262144
#define OFF_PARTS  1572864u    // up to 2097152
#define OFF_Y      3670016u    // 262144
#define OFF_X1N    3932160u    // 262144
#define OFF_X2N    4194304u    // 262144
#define OFF_LOG    4456448u    // 131072
#define OFF_STATS  4587520u    // 8

// ---------------------------------------------------------------------------
// Tiled fp32 GEMM: C_part[z][M][N] += A[M][K-chunk] * B[K-chunk][N]
// Block tile 128(m) x 64(n), thread tile 8x4, BK=16.
// B source: plain row-major (Bp != nullptr) or implicit im2col from
// xbuf[1024][256]: B[kg][bt] = x[kg/3][t + kg%3 - 1] (zero-padded in t).
// ---------------------------------------------------------------------------
__global__ __launch_bounds__(256) void gemm_k(
    const float* __restrict__ A, int lda,
    const float* __restrict__ Bp, int ldb,
    const float* __restrict__ xbuf,
    float* __restrict__ C,
    int M, int N, int Kz)
{
    __shared__ float As[BK][132];   // [k][m], padded
    __shared__ float Bs[BK][64];    // [k][n]

    const int tid = threadIdx.x;
    const int tx = tid & 15;        // n group (4 each)
    const int ty = tid >> 4;        // m group (8 each)
    const int n0 = blockIdx.x * TILE_N;
    const int m0 = blockIdx.y * TILE_M;
    const int kk0 = blockIdx.z * Kz;

    const int sa_m = tid >> 2;          // 0..63
    const int sa_c = (tid & 3) * 4;     // k offset
    const int sb_k = tid >> 4;          // 0..15
    const int sb_c = (tid & 15) * 4;    // n offset

    float4 acc[8];
    #pragma unroll
    for (int r = 0; r < 8; ++r) acc[r] = make_float4(0.f, 0.f, 0.f, 0.f);

    for (int kk = 0; kk < Kz; kk += BK) {
        const int kbase = kk0 + kk;
        // stage A (transposed into [k][m])
        #pragma unroll
        for (int p = 0; p < 2; ++p) {
            const int m = sa_m + p * 64;
            float4 av = *(const float4*)&A[(size_t)(m0 + m) * lda + kbase + sa_c];
            As[sa_c + 0][m] = av.x;
            As[sa_c + 1][m] = av.y;
            As[sa_c + 2][m] = av.z;
            As[sa_c + 3][m] = av.w;
        }
        // stage B
        if (Bp) {
            float4 bv = *(const float4*)&Bp[(size_t)(kbase + sb_k) * ldb + n0 + sb_c];
            *(float4*)&Bs[sb_k][sb_c] = bv;
        } else {
            const int kg = kbase + sb_k;
            const int i = kg / 3;
            const int r3 = kg - 3 * i;
            const int bt = n0 + sb_c;
            float v[4];
            #pragma unroll
            for (int j = 0; j < 4; ++j) {
                const int t = (bt + j) & 127;
                const int ts = t + r3 - 1;
                v[j] = ((unsigned)ts < 128u) ? xbuf[i * BT + bt + j + r3 - 1] : 0.f;
            }
            Bs[sb_k][sb_c + 0] = v[0];
            Bs[sb_k][sb_c + 1] = v[1];
            Bs[sb_k][sb_c + 2] = v[2];
            Bs[sb_k][sb_c + 3] = v[3];
        }
        __syncthreads();
        #pragma unroll
        for (int k = 0; k < BK; ++k) {
            float4 b4 = *(float4*)&Bs[k][tx * 4];
            float4 a0 = *(float4*)&As[k][ty * 8];
            float4 a1 = *(float4*)&As[k][ty * 8 + 4];
            float am[8] = {a0.x, a0.y, a0.z, a0.w, a1.x, a1.y, a1.z, a1.w};
            #pragma unroll
            for (int r = 0; r < 8; ++r) {
                acc[r].x += am[r] * b4.x;
                acc[r].y += am[r] * b4.y;
                acc[r].z += am[r] * b4.z;
                acc[r].w += am[r] * b4.w;
            }
        }
        __syncthreads();
    }

    float* Cp = C + (size_t)blockIdx.z * M * N + (size_t)(m0 + ty * 8) * N + n0 + tx * 4;
    #pragma unroll
    for (int r = 0; r < 8; ++r)
        *(float4*)&Cp[(size_t)r * N] = acc[r];
}

// ---------------------------------------------------------------------------
// Sum z partials, add bias (mode 0: none, 1: per-n, 2: per-m), optional relu,
// optional GN stats (sum/sumsq per b; layout [o][bt], b = (idx>>7)&1).
// ---------------------------------------------------------------------------
__global__ __launch_bounds__(256) void reduce_k(
    const float* __restrict__ parts, int z, int MN, int nshift,
    const float* __restrict__ bias, int bias_mode, int relu,
    float* __restrict__ out, float* __restrict__ stats)
{
    const int tid = threadIdx.x;
    float s0 = 0.f, q0 = 0.f, s1 = 0.f, q1 = 0.f;
    const int nmask = (1 << nshift) - 1;
    for (int idx = blockIdx.x * 256 + tid; idx < MN; idx += gridDim.x * 256) {
        float v = 0.f;
        for (int zz = 0; zz < z; ++zz) v += parts[(size_t)zz * MN + idx];
        if (bias_mode == 1) v += bias[idx & nmask];
        else if (bias_mode == 2) v += bias[idx >> nshift];
        if (relu) v = fmaxf(v, 0.f);
        out[idx] = v;
        if (stats) {
            if ((idx >> 7) & 1) { s1 += v; q1 += v * v; }
            else                { s0 += v; q0 += v * v; }
        }
    }
    if (stats) {
        __shared__ float4 sm[256];
        sm[tid] = make_float4(s0, q0, s1, q1);
        __syncthreads();
        for (int s = 128; s > 0; s >>= 1) {
            if (tid < s) {
                sm[tid].x += sm[tid + s].x;
                sm[tid].y += sm[tid + s].y;
                sm[tid].z += sm[tid + s].z;
                sm[tid].w += sm[tid + s].w;
            }
            __syncthreads();
        }
        if (tid == 0) {
            atomicAdd(&stats[0], sm[0].x);
            atomicAdd(&stats[1], sm[0].y);
            atomicAdd(&stats[2], sm[0].z);
            atomicAdd(&stats[3], sm[0].w);
        }
    }
}

// GroupNorm(1 group) apply: y [1024][256] -> out, stats = {sum,sumsq} per b.
__global__ __launch_bounds__(256) void gn_apply_k(
    const float* __restrict__ y, const float* __restrict__ stats,
    const float* __restrict__ g, const float* __restrict__ bet,
    float* __restrict__ out)
{
    const int idx = blockIdx.x * 256 + threadIdx.x;
    const float v = y[idx];
    const int o = idx >> 8;
    const int b = (idx >> 7) & 1;
    const float cnt = 131072.f;
    const float mu = stats[b * 2] / cnt;
    const float var = stats[b * 2 + 1] / cnt - mu * mu;
    const float rs = rsqrtf(var + EPSV);
    out[idx] = (v - mu) * rs * g[o] + bet[o];
}

// transpose text [256][1024] -> xT [1024][256]
__global__ __launch_bounds__(256) void transpose_k(
    const float* __restrict__ in, float* __restrict__ out)
{
    __shared__ float tile[32][33];
    const int i0 = blockIdx.x * 32, r0 = blockIdx.y * 32;
    const int tx = threadIdx.x & 31, ty = threadIdx.x >> 5;
    #pragma unroll
    for (int j = 0; j < 4; ++j)
        tile[ty + j * 8][tx] = in[(size_t)(r0 + ty + j * 8) * H_DIM + i0 + tx];
    __syncthreads();
    #pragma unroll
    for (int j = 0; j < 4; ++j)
        out[(size_t)(i0 + ty + j * 8) * BT + r0 + tx] = tile[tx][ty + j * 8];
}

// durations[bt] = softplus(sum_i x2n[i][bt]*w3[i] + b3)
__global__ __launch_bounds__(256) void conv3_k(
    const float* __restrict__ x, const float* __restrict__ w,
    const float* __restrict__ b3, float* __restrict__ out)
{
    __shared__ float red[8][32];
    const int lane = threadIdx.x & 31;
    const int ig = threadIdx.x >> 5;
    const int bt = blockIdx.x * 32 + lane;
    float s = 0.f;
    for (int i = ig * 128; i < ig * 128 + 128; ++i)
        s += x[(size_t)i * BT + bt] * w[i];
    red[ig][lane] = s;
    __syncthreads();
    if (ig == 0) {
        float t = red[0][lane] + red[1][lane] + red[2][lane] + red[3][lane]
                + red[4][lane] + red[5][lane] + red[6][lane] + red[7][lane];
        t += b3[0];
        out[bt] = fmaxf(t, 0.f) + log1pf(expf(-fabsf(t)));
    }
}

// logits[b][t][a] = sum_h relu(tp[b,t,h]+ap[b,a,h])*w2[h] + b2 - 0.1|a-4t|
// block: 4 t x 64 a, LDS-staged ap tiles.
__global__ __launch_bounds__(256) void logits_k(
    const float* __restrict__ tp, const float* __restrict__ ap,
    const float* __restrict__ w2, const float* __restrict__ b2,
    float* __restrict__ lg)
{
    __shared__ float tps[4][1024];
    __shared__ float w2s[1024];
    __shared__ float aps[64][68];

    const int b = blockIdx.z, t0 = blockIdx.y * 4, a0 = blockIdx.x * 64;
    const int tid = threadIdx.x;
    const int tl = tid >> 6, al = tid & 63;
    {
        const int row = tid >> 6;
        const int c = tid & 63;
        const float* src = tp + (size_t)(b * 128 + t0 + row) * H_DIM;
        #pragma unroll
        for (int p = 0; p < 4; ++p) {
            float4 v = *(const float4*)&src[(p * 64 + c) * 4];
            *(float4*)&tps[row][(p * 64 + c) * 4] = v;
        }
    }
    {
        float4 v = *(const float4*)&w2[tid * 4];
        *(float4*)&w2s[tid * 4] = v;
    }
    float acc = 0.f;
    const float* apb = ap + (size_t)(b * TA_N + a0) * H_DIM;
    const int sr = tid >> 4, sc = (tid & 15) * 4;
    for (int hh = 0; hh < H_DIM; hh += 64) {
        __syncthreads();
        #pragma unroll
        for (int p = 0; p < 4; ++p) {
            float4 v = *(const float4*)&apb[(size_t)(sr + p * 16) * H_DIM + hh + sc];
            *(float4*)&aps[sr + p * 16][sc] = v;
        }
        __syncthreads();
        #pragma unroll
        for (int h4 = 0; h4 < 64; h4 += 4) {
            float4 tv = *(const float4*)&tps[tl][hh + h4];
            float4 av = *(const float4*)&aps[al][h4];
            float4 wv = *(const float4*)&w2s[hh + h4];
            acc += fmaxf(tv.x + av.x, 0.f) * wv.x;
            acc += fmaxf(tv.y + av.y, 0.f) * wv.y;
            acc += fmaxf(tv.z + av.z, 0.f) * wv.z;
            acc += fmaxf(tv.w + av.w, 0.f) * wv.w;
        }
    }
    const int t = t0 + tl, a = a0 + al;
    const float lgv = acc + b2[0] - 0.1f * fabsf((float)a - 4.0f * (float)t);
    lg[(size_t)(b * 128 + t) * TA_N + a] = lgv;
}

// softmax over a (512) per (b,t) row; writes alignment to d_out.
__global__ __launch_bounds__(256) void softmax_k(
    const float* __restrict__ lg, float* __restrict__ out)
{
    __shared__ float red[256];
    const int row = blockIdx.x;
    const int tid = threadIdx.x;
    const float* src = lg + (size_t)row * TA_N;
    const float v0 = src[tid], v1 = src[tid + 256];
    float m = fmaxf(v0, v1);
    red[tid] = m;
    __syncthreads();
    for (int s = 128; s > 0; s >>= 1) {
        if (tid < s) red[tid] = fmaxf(red[tid], red[tid + s]);
        __syncthreads();
    }
    m = red[0];
    __syncthreads();
    const float e0 = expf(v0 - m), e1 = expf(v1 - m);
    red[tid] = e0 + e1;
    __syncthreads();
    for (int s = 128; s > 0; s >>= 1) {
        if (tid < s) red[tid] += red[tid + s];
        __syncthreads();
    }
    const float inv = 1.0f / red[0];
    out[(size_t)row * TA_N + tid] = e0 * inv;
    out[(size_t)row * TA_N + tid + 256] = e1 * inv;
}

extern "C" void kernel_launch(void* const* d_in, const int* in_sizes, int n_in,
                              void* d_out, int out_size, void* d_ws, size_t ws_size,
                              hipStream_t stream) {
    const float* text   = (const float*)d_in[0];
    const float* audio  = (const float*)d_in[1];
    const float* a_w1   = (const float*)d_in[2];
    const float* a_b1   = (const float*)d_in[3];
    const float* a_w2   = (const float*)d_in[4];
    const float* a_b2   = (const float*)d_in[5];
    const float* d_w1   = (const float*)d_in[6];
    const float* d_b1   = (const float*)d_in[7];
    const float* gn1_g  = (const float*)d_in[8];
    const float* gn1_b  = (const float*)d_in[9];
    const float* d_w2   = (const float*)d_in[10];
    const float* d_b2   = (const float*)d_in[11];
    const float* gn2_g  = (const float*)d_in[12];
    const float* gn2_b  = (const float*)d_in[13];
    const float* d_w3   = (const float*)d_in[14];
    const float* d_b3   = (const float*)d_in[15];

    float* ws   = (float*)d_ws;
    float* outf = (float*)d_out;

    hipMemsetAsync(ws + OFF_STATS, 0, 8 * sizeof(float), stream);

    // tp = text @ W1_top (+b1 in reduce). M=256,N=1024,K=1024, z=8.
    gemm_k<<<dim3(16, 2, 8), 256, 0, stream>>>(
        text, 1024, a_w1, 1024, nullptr, ws + OFF_PARTS, 256, 1024, 128);
    reduce_k<<<dim3(256), 256, 0, stream>>>(
        ws + OFF_PARTS, 8, 262144, 10, a_b1, 1, 0, ws + OFF_TP, nullptr);

    // ap = audio @ W1_bot. M=1024,N=1024,K=1024, z=2.
    gemm_k<<<dim3(16, 8, 2), 256, 0, stream>>>(
        audio, 1024, a_w1 + 1024 * 1024, 1024, nullptr, ws + OFF_PARTS, 1024, 1024, 512);
    reduce_k<<<dim3(256), 256, 0, stream>>>(
        ws + OFF_PARTS, 2, 1048576, 10, nullptr, 0, 0, ws + OFF_AP, nullptr);

    // transpose text -> xT [i][bt]
    transpose_k<<<dim3(32, 8), 256, 0, stream>>>(text, ws + OFF_XT);

    // conv1 (implicit im2col GEMM): M=1024,N=256,K=3072, z=8.
    gemm_k<<<dim3(4, 8, 8), 256, 0, stream>>>(
        d_w1, 3072, nullptr, 0, ws + OFF_XT, ws + OFF_PARTS, 1024, 256, 384);
    reduce_k<<<dim3(256), 256, 0, stream>>>(
        ws + OFF_PARTS, 8, 262144, 8, d_b1, 2, 1, ws + OFF_Y, ws + OFF_STATS);
    gn_apply_k<<<dim3(1024), 256, 0, stream>>>(
        ws + OFF_Y, ws + OFF_STATS, gn1_g, gn1_b, ws + OFF_X1N);

    // conv2
    gemm_k<<<dim3(4, 8, 8), 256, 0, stream>>>(
        d_w2, 3072, nullptr, 0, ws + OFF_X1N, ws + OFF_PARTS, 1024, 256, 384);
    reduce_k<<<dim3(256), 256, 0, stream>>>(
        ws + OFF_PARTS, 8, 262144, 8, d_b2, 2, 1, ws + OFF_Y, ws + OFF_STATS + 4);
    gn_apply_k<<<dim3(1024), 256, 0, stream>>>(
        ws + OFF_Y, ws + OFF_STATS + 4, gn2_g, gn2_b, ws + OFF_X2N);

    // conv3 + softplus -> durations
    conv3_k<<<dim3(8), 256, 0, stream>>>(
        ws + OFF_X2N, d_w3, d_b3, outf + 131072);

    // logits + softmax -> alignment
    logits_k<<<dim3(8, 32, 2), 256, 0, stream>>>(
        ws + OFF_TP, ws + OFF_AP, a_w2, a_b2, ws + OFF_LOG);
    softmax_k<<<dim3(256), 256, 0, stream>>>(ws + OFF_LOG, outf);
}

// Round 2
// 278.271 us; speedup vs baseline: 1.3509x; 1.3509x over previous
//
#include <hip/hip_runtime.h>
#include <hip/hip_bf16.h>

// ---------------------------------------------------------------------------
// MonotonicAlignmentSearch R1: bf16 MFMA GEMMs + fused conv/GN + bf16-apT logits.
// B=2, TT=128, TA=512, H=1024.
// ---------------------------------------------------------------------------

typedef __bf16 bf16_t;
typedef __bf16 bf16x8 __attribute__((ext_vector_type(8)));
typedef __bf16 bf16x4 __attribute__((ext_vector_type(4)));
typedef float  f32x4  __attribute__((ext_vector_type(4)));

#define EPSV 1e-5f

// ---- workspace offsets (bytes) --------------------------------------------
#define OFF_TEXTBF   0u          //  524288  bf16 text [256][1024]
#define OFF_AUDIOBF  524288u     // 2097152  bf16 audio [1024][1024]
#define OFF_W1T      2621440u    // 6291456  region: topT(2M)+botT(2M)+spare; later Wc(6M)
#define OFF_TP       8912896u    // 1048576  fp32 tp [256][1024]
#define OFF_APT      9961472u    // 2097152  bf16 apT [2][1024][512]
#define OFF_PARTS    12058624u   // 4194304  fp32 split-k partials; later logits fp32 (524288)
#define OFF_XP0      16252928u   //  532480  bf16 xp0 [2][130][1024] (padded text)
#define OFF_XP1      16785408u   //  532480  bf16 xp1 [2][130][1024]
#define OFF_X2N      17317888u   //  524288  bf16 x2n [256][1024]
#define OFF_STATS    17842176u   //      32  8 floats
// total 17842208 bytes (< 18.35 MB known-good)

// ---------------------------------------------------------------------------
// prep: fp32 -> bf16 for text (flat + padded xp0) and audio
// ---------------------------------------------------------------------------
__global__ __launch_bounds__(256) void cvt_act_k(
    const float* __restrict__ text, const float* __restrict__ audio,
    bf16_t* __restrict__ text_bf, bf16_t* __restrict__ xp0,
    bf16_t* __restrict__ audio_bf)
{
    const int e = (blockIdx.x * 256 + threadIdx.x) * 4;   // 1310720 total
    if (e < 262144) {
        float4 v = *(const float4*)&text[e];
        bf16x4 o; o[0] = (bf16_t)v.x; o[1] = (bf16_t)v.y; o[2] = (bf16_t)v.z; o[3] = (bf16_t)v.w;
        *(bf16x4*)&text_bf[e] = o;
        const int bt = e >> 10, h = e & 1023;
        const int b = bt >> 7, t = bt & 127;
        *(bf16x4*)&xp0[(size_t)(b * 130 + 1 + t) * 1024 + h] = o;
    } else {
        const int ea = e - 262144;
        float4 v = *(const float4*)&audio[ea];
        bf16x4 o; o[0] = (bf16_t)v.x; o[1] = (bf16_t)v.y; o[2] = (bf16_t)v.z; o[3] = (bf16_t)v.w;
        *(bf16x4*)&audio_bf[ea] = o;
    }
}

// a_w1 [2048][1024] fp32 -> W1topT [1024][1024] bf16, W1botT bf16 (transposed)
__global__ __launch_bounds__(256) void cvt_w1T_k(
    const float* __restrict__ w1, bf16_t* __restrict__ topT, bf16_t* __restrict__ botT)
{
    __shared__ float tile[32][33];
    const int bx = blockIdx.x, by = blockIdx.y;       // (32, 64)
    const int tx = threadIdx.x & 31, ty = threadIdx.x >> 5;
    #pragma unroll
    for (int j = 0; j < 4; ++j)
        tile[ty + j * 8][tx] = w1[(size_t)(by * 32 + ty + j * 8) * 1024 + bx * 32 + tx];
    __syncthreads();
    bf16_t* out = (by < 32) ? topT : botT;
    const int hbase = (by & 31) * 32;
    #pragma unroll
    for (int j = 0; j < 4; ++j) {
        const int d = bx * 32 + ty + j * 8;
        out[(size_t)d * 1024 + hbase + tx] = (bf16_t)tile[tx][ty + j * 8];
    }
}

// d_w [1024][1024*3] fp32 ([o][i][r]) -> Wc [3][1024][1024] bf16 ([r][o][i])
__global__ __launch_bounds__(256) void cvt_wc_k(
    const float* __restrict__ w, bf16_t* __restrict__ wc)
{
    const int t = blockIdx.x * 256 + threadIdx.x;     // 262144 threads
    const int o = t >> 8, i4 = t & 255;               // 4 i's per thread
    const float* src = w + (size_t)o * 3072 + i4 * 12;
    float4 v0 = *(const float4*)&src[0];
    float4 v1 = *(const float4*)&src[4];
    float4 v2 = *(const float4*)&src[8];
    const float f[12] = {v0.x, v0.y, v0.z, v0.w, v1.x, v1.y, v1.z, v1.w, v2.x, v2.y, v2.z, v2.w};
    #pragma unroll
    for (int r = 0; r < 3; ++r) {
        bf16x4 o4;
        #pragma unroll
        for (int j = 0; j < 4; ++j) o4[j] = (bf16_t)f[j * 3 + r];
        *(bf16x4*)&wc[(size_t)r * 1048576 + (size_t)o * 1024 + i4 * 4] = o4;
    }
}

// ---------------------------------------------------------------------------
// GEMMs: 1-wave blocks, 64x64 tile, direct bf16x8 fragment loads (no LDS).
// C[m][n] = sum_k A[m][k] * Bt[n][k]; both operands k-contiguous rows.
// A-frag lane l: m = l&15, k = (l>>4)*8+j ; B-frag: n = l&15 same k.
// C/D lane l reg r: row m = (l>>4)*4+r, col n = l&15.
// ---------------------------------------------------------------------------
__global__ __launch_bounds__(64) void gemm_tp_k(
    const bf16_t* __restrict__ A, const bf16_t* __restrict__ Bt,
    float* __restrict__ parts)
{
    const int l = threadIdx.x;
    const int n0 = blockIdx.x * 64, m0 = blockIdx.y * 64, k0 = blockIdx.z * 256;
    const int lm = l & 15, lk = (l >> 4) * 8;
    f32x4 acc[4][4];
    #pragma unroll
    for (int mt = 0; mt < 4; ++mt)
        #pragma unroll
        for (int nt = 0; nt < 4; ++nt) acc[mt][nt] = (f32x4)(0.0f);
    const bf16_t* Ap = A + (size_t)(m0 + lm) * 1024 + k0 + lk;
    const bf16_t* Bp = Bt + (size_t)(n0 + lm) * 1024 + k0 + lk;
    for (int kk = 0; kk < 256; kk += 32) {
        bf16x8 af[4], bfr[4];
        #pragma unroll
        for (int i = 0; i < 4; ++i) {
            af[i]  = *(const bf16x8*)(Ap + (size_t)i * 16384 + kk);
            bfr[i] = *(const bf16x8*)(Bp + (size_t)i * 16384 + kk);
        }
        #pragma unroll
        for (int mt = 0; mt < 4; ++mt)
            #pragma unroll
            for (int nt = 0; nt < 4; ++nt)
                acc[mt][nt] = __builtin_amdgcn_mfma_f32_16x16x32_bf16(af[mt], bfr[nt], acc[mt][nt], 0, 0, 0);
    }
    float* P = parts + (size_t)blockIdx.z * 262144;
    #pragma unroll
    for (int mt = 0; mt < 4; ++mt) {
        const int row = m0 + mt * 16 + (l >> 4) * 4;
        #pragma unroll
        for (int nt = 0; nt < 4; ++nt) {
            const int col = n0 + nt * 16 + lm;
            #pragma unroll
            for (int r = 0; r < 4; ++r)
                P[(size_t)(row + r) * 1024 + col] = acc[mt][nt][r];
        }
    }
}

// ap GEMM: audio_bf x W1botT, K=1024, epilogue -> apT bf16 [2][1024][512]
__global__ __launch_bounds__(64) void gemm_ap_k(
    const bf16_t* __restrict__ A, const bf16_t* __restrict__ Bt,
    bf16_t* __restrict__ apT)
{
    __shared__ bf16_t T[64][66];
    const int l = threadIdx.x;
    const int n0 = blockIdx.x * 64, m0 = blockIdx.y * 64;
    const int lm = l & 15, lk = (l >> 4) * 8;
    f32x4 acc[4][4];
    #pragma unroll
    for (int mt = 0; mt < 4; ++mt)
        #pragma unroll
        for (int nt = 0; nt < 4; ++nt) acc[mt][nt] = (f32x4)(0.0f);
    const bf16_t* Ap = A + (size_t)(m0 + lm) * 1024 + lk;
    const bf16_t* Bp = Bt + (size_t)(n0 + lm) * 1024 + lk;
    for (int kk = 0; kk < 1024; kk += 32) {
        bf16x8 af[4], bfr[4];
        #pragma unroll
        for (int i = 0; i < 4; ++i) {
            af[i]  = *(const bf16x8*)(Ap + (size_t)i * 16384 + kk);
            bfr[i] = *(const bf16x8*)(Bp + (size_t)i * 16384 + kk);
        }
        #pragma unroll
        for (int mt = 0; mt < 4; ++mt)
            #pragma unroll
            for (int nt = 0; nt < 4; ++nt)
                acc[mt][nt] = __builtin_amdgcn_mfma_f32_16x16x32_bf16(af[mt], bfr[nt], acc[mt][nt], 0, 0, 0);
    }
    #pragma unroll
    for (int mt = 0; mt < 4; ++mt)
        #pragma unroll
        for (int nt = 0; nt < 4; ++nt)
            #pragma unroll
            for (int r = 0; r < 4; ++r)
                T[mt * 16 + (l >> 4) * 4 + r][nt * 16 + lm] = (bf16_t)acc[mt][nt][r];
    __syncthreads();
    const int b = m0 >> 9, a0 = m0 & 511;
    bf16_t* dst = apT + (size_t)b * 524288 + a0 + l;
    for (int dr = 0; dr < 64; ++dr)
        dst[(size_t)(n0 + dr) * 512] = T[l][dr];
}

// conv GEMM: Wc [3][1024][1024] x padded activations xp [2][130][1024]
// C[o][bt] = sum_r sum_i Wc[r][o][i] * xp[b*130 + t + r][i]; split-k over i (z=4)
__global__ __launch_bounds__(64) void gemm_conv_k(
    const bf16_t* __restrict__ Wc, const bf16_t* __restrict__ xp,
    float* __restrict__ parts)
{
    const int l = threadIdx.x;
    const int n0 = blockIdx.x * 64, m0 = blockIdx.y * 64, i0 = blockIdx.z * 256;
    const int lm = l & 15, lk = (l >> 4) * 8;
    const int b = n0 >> 7, tbase = n0 & 127;
    f32x4 acc[4][4];
    #pragma unroll
    for (int mt = 0; mt < 4; ++mt)
        #pragma unroll
        for (int nt = 0; nt < 4; ++nt) acc[mt][nt] = (f32x4)(0.0f);
    const bf16_t* aq = Wc + (size_t)(m0 + lm) * 1024 + i0 + lk;
    const bf16_t* bq = xp + (size_t)(b * 130 + tbase + lm) * 1024 + i0 + lk;
    #pragma unroll
    for (int r = 0; r < 3; ++r) {
        const bf16_t* ar = aq + (size_t)r * 1048576;
        const bf16_t* br = bq + (size_t)r * 1024;
        for (int kk = 0; kk < 256; kk += 32) {
            bf16x8 af[4], bfr[4];
            #pragma unroll
            for (int i = 0; i < 4; ++i) {
                af[i]  = *(const bf16x8*)(ar + (size_t)i * 16384 + kk);
                bfr[i] = *(const bf16x8*)(br + (size_t)i * 16384 + kk);
            }
            #pragma unroll
            for (int mt = 0; mt < 4; ++mt)
                #pragma unroll
                for (int nt = 0; nt < 4; ++nt)
                    acc[mt][nt] = __builtin_amdgcn_mfma_f32_16x16x32_bf16(af[mt], bfr[nt], acc[mt][nt], 0, 0, 0);
        }
    }
    float* P = parts + (size_t)blockIdx.z * 262144;
    #pragma unroll
    for (int mt = 0; mt < 4; ++mt) {
        const int row = m0 + mt * 16 + (l >> 4) * 4;
        #pragma unroll
        for (int nt = 0; nt < 4; ++nt) {
            const int col = n0 + nt * 16 + lm;
            #pragma unroll
            for (int r = 0; r < 4; ++r)
                P[(size_t)(row + r) * 256 + col] = acc[mt][nt][r];
        }
    }
}

// ---------------------------------------------------------------------------
// reduce split-k tp partials + bias -> tp fp32
// ---------------------------------------------------------------------------
__global__ __launch_bounds__(256) void reduce_tp_k(
    const float* __restrict__ parts, const float* __restrict__ b1,
    float* __restrict__ tp)
{
    const int idx4 = blockIdx.x * 256 + threadIdx.x;  // 65536 float4s
    const float4* p = (const float4*)parts;
    float4 v = p[idx4];
    #pragma unroll
    for (int z = 1; z < 4; ++z) {
        float4 w = p[z * 65536 + idx4];
        v.x += w.x; v.y += w.y; v.z += w.z; v.w += w.w;
    }
    float4 bv = ((const float4*)b1)[idx4 & 255];
    v.x += bv.x; v.y += bv.y; v.z += bv.z; v.w += bv.w;
    ((float4*)tp)[idx4] = v;
}

// reduce conv partials [4][1024][256] -> bias+relu -> bf16 transposed [bt][o]
// (written into padded xp or flat buffer) + GN stats atomics.
__global__ __launch_bounds__(256) void reduce_convT_k(
    const float* __restrict__ parts, const float* __restrict__ bias,
    bf16_t* __restrict__ out, int rowsPerB, int rowOff,
    float* __restrict__ stats)
{
    __shared__ float T[64][65];
    __shared__ float reds[256], redq[256];
    const int tid = threadIdx.x;
    const int bt0 = blockIdx.x * 64, o0 = blockIdx.y * 64;
    const int b = bt0 >> 7;
    const int ro = tid >> 2, cq = tid & 3;
    float s = 0.f, q = 0.f;
    const float bv = bias[o0 + ro];
    #pragma unroll
    for (int j = 0; j < 4; ++j) {
        const int c4 = cq * 4 + j;                 // float4 col 0..15
        const float4* src = (const float4*)(parts + (size_t)(o0 + ro) * 256 + bt0) + c4;
        float4 v = src[0];
        #pragma unroll
        for (int z = 1; z < 4; ++z) {
            float4 w = src[z * 65536];
            v.x += w.x; v.y += w.y; v.z += w.z; v.w += w.w;
        }
        v.x = fmaxf(v.x + bv, 0.f); v.y = fmaxf(v.y + bv, 0.f);
        v.z = fmaxf(v.z + bv, 0.f); v.w = fmaxf(v.w + bv, 0.f);
        T[ro][c4 * 4 + 0] = v.x; T[ro][c4 * 4 + 1] = v.y;
        T[ro][c4 * 4 + 2] = v.z; T[ro][c4 * 4 + 3] = v.w;
        s += v.x + v.y + v.z + v.w;
        q += v.x * v.x + v.y * v.y + v.z * v.z + v.w * v.w;
    }
    reds[tid] = s; redq[tid] = q;
    __syncthreads();
    // transposed write: thread -> (bt row, 16 o's)
    {
        const int rb = tid & 63, og = tid >> 6;    // og 0..3 -> o range og*16..+16
        bf16x8 o8a, o8b;
        #pragma unroll
        for (int j = 0; j < 8; ++j) o8a[j] = (bf16_t)T[og * 16 + j][rb];
        #pragma unroll
        for (int j = 0; j < 8; ++j) o8b[j] = (bf16_t)T[og * 16 + 8 + j][rb];
        const int t = (bt0 & 127) + rb;
        bf16_t* dst = out + (size_t)(b * rowsPerB + rowOff + t) * 1024 + o0 + og * 16;
        *(bf16x8*)dst = o8a;
        *(bf16x8*)(dst + 8) = o8b;
    }
    for (int step = 128; step > 0; step >>= 1) {
        if (tid < step) { reds[tid] += reds[tid + step]; redq[tid] += redq[tid + step]; }
        __syncthreads();
    }
    if (tid == 0) {
        atomicAdd(&stats[b * 2], reds[0]);
        atomicAdd(&stats[b * 2 + 1], redq[0]);
    }
}

// GroupNorm apply in-place on bf16 buffer (padded or flat layout)
__global__ __launch_bounds__(256) void gn_apply_k(
    bf16_t* __restrict__ buf, int rowsPerB, int rowOff,
    const float* __restrict__ stats,
    const float* __restrict__ g, const float* __restrict__ bet)
{
    const int idx4 = blockIdx.x * 256 + threadIdx.x;  // 65536 groups of 4
    const int e = idx4 * 4;
    const int bt = e >> 10, o = e & 1023;
    const int b = bt >> 7, t = bt & 127;
    bf16_t* p = buf + (size_t)(b * rowsPerB + rowOff + t) * 1024 + o;
    const float cnt = 131072.f;
    const float mu = stats[b * 2] / cnt;
    const float var = stats[b * 2 + 1] / cnt - mu * mu;
    const float rs = rsqrtf(var + EPSV);
    bf16x4 v = *(bf16x4*)p;
    float4 gv = *(const float4*)&g[o];
    float4 bv = *(const float4*)&bet[o];
    bf16x4 ov;
    ov[0] = (bf16_t)(((float)v[0] - mu) * rs * gv.x + bv.x);
    ov[1] = (bf16_t)(((float)v[1] - mu) * rs * gv.y + bv.y);
    ov[2] = (bf16_t)(((float)v[2] - mu) * rs * gv.z + bv.z);
    ov[3] = (bf16_t)(((float)v[3] - mu) * rs * gv.w + bv.w);
    *(bf16x4*)p = ov;
}

// durations[bt] = softplus(dot(x2n[bt][:], w3) + b3); one wave per row.
__global__ __launch_bounds__(256) void conv3_k(
    const bf16_t* __restrict__ x, const float* __restrict__ w3,
    const float* __restrict__ b3, float* __restrict__ out)
{
    const int lane = threadIdx.x & 63, w = threadIdx.x >> 6;
    const int bt = blockIdx.x * 4 + w;
    const bf16_t* row = x + (size_t)bt * 1024 + lane * 16;
    bf16x8 v0 = *(const bf16x8*)row;
    bf16x8 v1 = *(const bf16x8*)(row + 8);
    const float* wp = w3 + lane * 16;
    float s = 0.f;
    #pragma unroll
    for (int j = 0; j < 8; ++j) s += (float)v0[j] * wp[j];
    #pragma unroll
    for (int j = 0; j < 8; ++j) s += (float)v1[j] * wp[8 + j];
    #pragma unroll
    for (int off = 32; off > 0; off >>= 1) s += __shfl_down(s, off);
    if (lane == 0) {
        const float t = s + b3[0];
        out[bt] = fmaxf(t, 0.f) + log1pf(expf(-fabsf(t)));
    }
}

// logits[b][t][a] = sum_h relu(tp[b,t,h] + apT[b,h,a]) * w2[h] + b2 - 0.1|a-4t|
__global__ __launch_bounds__(256) void logits_k(
    const float* __restrict__ tp, const bf16_t* __restrict__ apT,
    const float* __restrict__ w2, const float* __restrict__ b2,
    float* __restrict__ lg)
{
    const int a = blockIdx.x * 256 + threadIdx.x;
    const int t0 = blockIdx.y * 2, b = blockIdx.z;
    const float* tp0 = tp + (size_t)(b * 128 + t0) * 1024;
    const float* tp1 = tp0 + 1024;
    const bf16_t* ap = apT + (size_t)b * 524288 + a;
    float acc0 = 0.f, acc1 = 0.f;
    #pragma unroll 4
    for (int h = 0; h < 1024; ++h) {
        const float av = (float)ap[(size_t)h * 512];
        const float wv = w2[h];
        acc0 += fmaxf(tp0[h] + av, 0.f) * wv;
        acc1 += fmaxf(tp1[h] + av, 0.f) * wv;
    }
    const float b2v = b2[0];
    const float fa = (float)a;
    float* dst = lg + (size_t)(b * 128 + t0) * 512 + a;
    dst[0]   = acc0 + b2v - 0.1f * fabsf(fa - 4.0f * (float)t0);
    dst[512] = acc1 + b2v - 0.1f * fabsf(fa - 4.0f * (float)(t0 + 1));
}

// softmax over a (512) per (b,t) row
__global__ __launch_bounds__(256) void softmax_k(
    const float* __restrict__ lg, float* __restrict__ out)
{
    __shared__ float red[256];
    const int row = blockIdx.x, tid = threadIdx.x;
    const float* src = lg + (size_t)row * 512;
    const float v0 = src[tid], v1 = src[tid + 256];
    float m = fmaxf(v0, v1);
    red[tid] = m;
    __syncthreads();
    for (int s = 128; s > 0; s >>= 1) {
        if (tid < s) red[tid] = fmaxf(red[tid], red[tid + s]);
        __syncthreads();
    }
    m = red[0];
    __syncthreads();
    const float e0 = expf(v0 - m), e1 = expf(v1 - m);
    red[tid] = e0 + e1;
    __syncthreads();
    for (int s = 128; s > 0; s >>= 1) {
        if (tid < s) red[tid] += red[tid + s];
        __syncthreads();
    }
    const float inv = 1.0f / red[0];
    out[(size_t)row * 512 + tid] = e0 * inv;
    out[(size_t)row * 512 + tid + 256] = e1 * inv;
}

extern "C" void kernel_launch(void* const* d_in, const int* in_sizes, int n_in,
                              void* d_out, int out_size, void* d_ws, size_t ws_size,
                              hipStream_t stream) {
    const float* text   = (const float*)d_in[0];
    const float* audio  = (const float*)d_in[1];
    const float* a_w1   = (const float*)d_in[2];
    const float* a_b1   = (const float*)d_in[3];
    const float* a_w2   = (const float*)d_in[4];
    const float* a_b2   = (const float*)d_in[5];
    const float* d_w1   = (const float*)d_in[6];
    const float* d_b1   = (const float*)d_in[7];
    const float* gn1_g  = (const float*)d_in[8];
    const float* gn1_b  = (const float*)d_in[9];
    const float* d_w2   = (const float*)d_in[10];
    const float* d_b2   = (const float*)d_in[11];
    const float* gn2_g  = (const float*)d_in[12];
    const float* gn2_b  = (const float*)d_in[13];
    const float* d_w3   = (const float*)d_in[14];
    const float* d_b3   = (const float*)d_in[15];

    char* ws = (char*)d_ws;
    float* outf = (float*)d_out;

    bf16_t* text_bf  = (bf16_t*)(ws + OFF_TEXTBF);
    bf16_t* audio_bf = (bf16_t*)(ws + OFF_AUDIOBF);
    bf16_t* w1topT   = (bf16_t*)(ws + OFF_W1T);
    bf16_t* w1botT   = (bf16_t*)(ws + OFF_W1T + 2097152);
    bf16_t* wc       = (bf16_t*)(ws + OFF_W1T);        // overlays W1T after ap gemm
    float*  tp       = (float*) (ws + OFF_TP);
    bf16_t* apT      = (bf16_t*)(ws + OFF_APT);
    float*  parts    = (float*) (ws + OFF_PARTS);
    float*  logits   = (float*) (ws + OFF_PARTS);      // overlays parts at the end
    bf16_t* xp0      = (bf16_t*)(ws + OFF_XP0);
    bf16_t* xp1      = (bf16_t*)(ws + OFF_XP1);
    bf16_t* x2n      = (bf16_t*)(ws + OFF_X2N);
    float*  stats    = (float*) (ws + OFF_STATS);

    // zero padded activation buffers + stats (single contiguous memset)
    hipMemsetAsync(ws + OFF_XP0, 0, 532480u + 532480u + 524288u + 32u, stream);

    // prep
    cvt_act_k<<<dim3(1280), 256, 0, stream>>>(text, audio, text_bf, xp0, audio_bf);
    cvt_w1T_k<<<dim3(32, 64), 256, 0, stream>>>(a_w1, w1topT, w1botT);

    // tp = text @ W1_top + b1   (split-k z=4)
    gemm_tp_k<<<dim3(16, 4, 4), 64, 0, stream>>>(text_bf, w1topT, parts);
    reduce_tp_k<<<dim3(256), 256, 0, stream>>>(parts, a_b1, tp);

    // apT = (audio @ W1_bot)^T  bf16
    gemm_ap_k<<<dim3(16, 16), 64, 0, stream>>>(audio_bf, w1botT, apT);

    // conv1 -> GN1
    cvt_wc_k<<<dim3(1024), 256, 0, stream>>>(d_w1, wc);
    gemm_conv_k<<<dim3(4, 16, 4), 64, 0, stream>>>(wc, xp0, parts);
    reduce_convT_k<<<dim3(4, 16), 256, 0, stream>>>(parts, d_b1, xp1, 130, 1, stats);
    gn_apply_k<<<dim3(256), 256, 0, stream>>>(xp1, 130, 1, stats, gn1_g, gn1_b);

    // conv2 -> GN2
    cvt_wc_k<<<dim3(1024), 256, 0, stream>>>(d_w2, wc);
    gemm_conv_k<<<dim3(4, 16, 4), 64, 0, stream>>>(wc, xp1, parts);
    reduce_convT_k<<<dim3(4, 16), 256, 0, stream>>>(parts, d_b2, x2n, 128, 0, stats + 4);
    gn_apply_k<<<dim3(256), 256, 0, stream>>>(x2n, 128, 0, stats + 4, gn2_g, gn2_b);

    // conv3 + softplus -> durations
    conv3_k<<<dim3(64), 256, 0, stream>>>(x2n, d_w3, d_b3, outf + 131072);

    // logits + softmax -> alignment
    logits_k<<<dim3(2, 64, 2), 256, 0, stream>>>(tp, apT, a_w2, a_b2, logits);
    softmax_k<<<dim3(256), 256, 0, stream>>>(logits, outf);
}

// Round 3
// 244.477 us; speedup vs baseline: 1.5376x; 1.1382x over previous
//
#include <hip/hip_runtime.h>
#include <hip/hip_bf16.h>

// ---------------------------------------------------------------------------
// MonotonicAlignmentSearch R3: 32x64 MFMA wave-tiles + split-k, natural-layout
// ap (no transpose), h-vectorized LDS logits with h-split, fused combine.
// B=2, TT=128, TA=512, H=1024.
// ---------------------------------------------------------------------------

typedef __bf16 bf16_t;
typedef __bf16 bf16x8 __attribute__((ext_vector_type(8)));
typedef __bf16 bf16x4 __attribute__((ext_vector_type(4)));
typedef float  f32x4  __attribute__((ext_vector_type(4)));

#define EPSV 1e-5f

// ---- workspace offsets (bytes), total 17842208 (== R1 proven size) --------
#define OFF_TEXTBF   0u          //  524288  bf16 text [256][1024]
#define OFF_AUDIOBF  524288u     // 2097152  bf16 audio [1024][1024]
#define OFF_W1T      2621440u    // 6291456  w1topT(2M)+w1botT(2M); later wc(6M)
#define OFF_TPBF     8912896u    //  524288  bf16 tp [256][1024] (bias folded)
#define OFF_APBF     9437184u    // 2097152  bf16 ap [2][512][1024] (h-contig)
#define OFF_PARTS    11534336u   // 4194304  fp32 split-k partials
#define OFF_LP       15728640u   // 1048576  logits partials [2][2][512][128] f32
                                 //          (x2n bf16 [256][1024] overlays, earlier)
#define OFF_XP0      16777216u   //  532480  bf16 xp0 [2][130][1024] (zero-pad rows)
#define OFF_XP1      17309696u   //  532480  bf16 xp1 [2][130][1024]
#define OFF_STATS    17842176u   //      32  8 floats (GN stats)

// ---------------------------------------------------------------------------
// prep: fp32 -> bf16 for text (flat + padded xp0) and audio
// ---------------------------------------------------------------------------
__global__ __launch_bounds__(256) void cvt_act_k(
    const float* __restrict__ text, const float* __restrict__ audio,
    bf16_t* __restrict__ text_bf, bf16_t* __restrict__ xp0,
    bf16_t* __restrict__ audio_bf)
{
    const int e = (blockIdx.x * 256 + threadIdx.x) * 4;   // 1310720 total
    if (e < 262144) {
        float4 v = *(const float4*)&text[e];
        bf16x4 o; o[0] = (bf16_t)v.x; o[1] = (bf16_t)v.y; o[2] = (bf16_t)v.z; o[3] = (bf16_t)v.w;
        *(bf16x4*)&text_bf[e] = o;
        const int bt = e >> 10, h = e & 1023;
        const int b = bt >> 7, t = bt & 127;
        *(bf16x4*)&xp0[(size_t)(b * 130 + 1 + t) * 1024 + h] = o;
    } else {
        const int ea = e - 262144;
        float4 v = *(const float4*)&audio[ea];
        bf16x4 o; o[0] = (bf16_t)v.x; o[1] = (bf16_t)v.y; o[2] = (bf16_t)v.z; o[3] = (bf16_t)v.w;
        *(bf16x4*)&audio_bf[ea] = o;
    }
}

// a_w1 [2048][1024] fp32 -> W1topT [1024][1024] bf16, W1botT bf16 (transposed)
__global__ __launch_bounds__(256) void cvt_w1T_k(
    const float* __restrict__ w1, bf16_t* __restrict__ topT, bf16_t* __restrict__ botT)
{
    __shared__ float tile[32][33];
    const int bx = blockIdx.x, by = blockIdx.y;       // (32, 64)
    const int tx = threadIdx.x & 31, ty = threadIdx.x >> 5;
    #pragma unroll
    for (int j = 0; j < 4; ++j)
        tile[ty + j * 8][tx] = w1[(size_t)(by * 32 + ty + j * 8) * 1024 + bx * 32 + tx];
    __syncthreads();
    bf16_t* out = (by < 32) ? topT : botT;
    const int hbase = (by & 31) * 32;
    #pragma unroll
    for (int j = 0; j < 4; ++j) {
        const int d = bx * 32 + ty + j * 8;
        out[(size_t)d * 1024 + hbase + tx] = (bf16_t)tile[tx][ty + j * 8];
    }
}

// d_w [1024][1024*3] fp32 ([o][i][r]) -> Wc [3][1024][1024] bf16 ([r][o][i])
__global__ __launch_bounds__(256) void cvt_wc_k(
    const float* __restrict__ w, bf16_t* __restrict__ wc)
{
    const int t = blockIdx.x * 256 + threadIdx.x;     // 262144 threads
    const int o = t >> 8, i4 = t & 255;
    const float* src = w + (size_t)o * 3072 + i4 * 12;
    float4 v0 = *(const float4*)&src[0];
    float4 v1 = *(const float4*)&src[4];
    float4 v2 = *(const float4*)&src[8];
    const float f[12] = {v0.x, v0.y, v0.z, v0.w, v1.x, v1.y, v1.z, v1.w, v2.x, v2.y, v2.z, v2.w};
    #pragma unroll
    for (int r = 0; r < 3; ++r) {
        bf16x4 o4;
        #pragma unroll
        for (int j = 0; j < 4; ++j) o4[j] = (bf16_t)f[j * 3 + r];
        *(bf16x4*)&wc[(size_t)r * 1048576 + (size_t)o * 1024 + i4 * 4] = o4;
    }
}

// ---------------------------------------------------------------------------
// 32x64 wave-tile MFMA GEMMs (1 wave/block), direct bf16x8 fragment loads.
// A-frag lane l: m = l&15 (+16*frag), k = (l>>4)*8+j.
// C/D lane l reg r: row = (l>>4)*4+r, col = l&15.
// ---------------------------------------------------------------------------

// tp partial: C[bt][d] over k-chunk 512 (z=2)
__global__ __launch_bounds__(64) void gemm_tp_k(
    const bf16_t* __restrict__ A, const bf16_t* __restrict__ Bt,
    float* __restrict__ parts)
{
    const int l = threadIdx.x;
    const int n0 = blockIdx.x * 64, m0 = blockIdx.y * 32, k0 = blockIdx.z * 512;
    const int lm = l & 15, lk = (l >> 4) * 8;
    f32x4 acc[2][4];
    #pragma unroll
    for (int mt = 0; mt < 2; ++mt)
        #pragma unroll
        for (int nt = 0; nt < 4; ++nt) acc[mt][nt] = (f32x4)(0.0f);
    const bf16_t* Ap = A + (size_t)(m0 + lm) * 1024 + k0 + lk;
    const bf16_t* Bp = Bt + (size_t)(n0 + lm) * 1024 + k0 + lk;
    for (int kk = 0; kk < 512; kk += 32) {
        bf16x8 af[2], bfr[4];
        #pragma unroll
        for (int i = 0; i < 2; ++i) af[i] = *(const bf16x8*)(Ap + (size_t)i * 16384 + kk);
        #pragma unroll
        for (int i = 0; i < 4; ++i) bfr[i] = *(const bf16x8*)(Bp + (size_t)i * 16384 + kk);
        #pragma unroll
        for (int mt = 0; mt < 2; ++mt)
            #pragma unroll
            for (int nt = 0; nt < 4; ++nt)
                acc[mt][nt] = __builtin_amdgcn_mfma_f32_16x16x32_bf16(af[mt], bfr[nt], acc[mt][nt], 0, 0, 0);
    }
    float* P = parts + (size_t)blockIdx.z * 262144;
    #pragma unroll
    for (int mt = 0; mt < 2; ++mt) {
        const int row = m0 + mt * 16 + (l >> 4) * 4;
        #pragma unroll
        for (int nt = 0; nt < 4; ++nt) {
            const int col = n0 + nt * 16 + lm;
            #pragma unroll
            for (int r = 0; r < 4; ++r)
                P[(size_t)(row + r) * 1024 + col] = acc[mt][nt][r];
        }
    }
}

// reduce tp partials (z=2) + bias -> bf16 tp
__global__ __launch_bounds__(256) void reduce_tp_k(
    const float* __restrict__ parts, const float* __restrict__ b1,
    bf16_t* __restrict__ tp_bf)
{
    const int idx4 = blockIdx.x * 256 + threadIdx.x;  // 65536 float4s
    const float4* p = (const float4*)parts;
    float4 v = p[idx4];
    float4 w = p[65536 + idx4];
    float4 bv = ((const float4*)b1)[idx4 & 255];
    bf16x4 o;
    o[0] = (bf16_t)(v.x + w.x + bv.x);
    o[1] = (bf16_t)(v.y + w.y + bv.y);
    o[2] = (bf16_t)(v.z + w.z + bv.z);
    o[3] = (bf16_t)(v.w + w.w + bv.w);
    ((bf16x4*)tp_bf)[idx4] = o;
}

// ap GEMM: audio_bf x W1botT, K=1024, direct bf16 epilogue to ap[m][n] via LDS.
__global__ __launch_bounds__(64) void gemm_ap_k(
    const bf16_t* __restrict__ A, const bf16_t* __restrict__ Bt,
    bf16_t* __restrict__ out)
{
    __shared__ bf16_t T[32][72];
    const int l = threadIdx.x;
    const int n0 = blockIdx.x * 64, m0 = blockIdx.y * 32;
    const int lm = l & 15, lk = (l >> 4) * 8;
    f32x4 acc[2][4];
    #pragma unroll
    for (int mt = 0; mt < 2; ++mt)
        #pragma unroll
        for (int nt = 0; nt < 4; ++nt) acc[mt][nt] = (f32x4)(0.0f);
    const bf16_t* Ap = A + (size_t)(m0 + lm) * 1024 + lk;
    const bf16_t* Bp = Bt + (size_t)(n0 + lm) * 1024 + lk;
    for (int kk = 0; kk < 1024; kk += 32) {
        bf16x8 af[2], bfr[4];
        #pragma unroll
        for (int i = 0; i < 2; ++i) af[i] = *(const bf16x8*)(Ap + (size_t)i * 16384 + kk);
        #pragma unroll
        for (int i = 0; i < 4; ++i) bfr[i] = *(const bf16x8*)(Bp + (size_t)i * 16384 + kk);
        #pragma unroll
        for (int mt = 0; mt < 2; ++mt)
            #pragma unroll
            for (int nt = 0; nt < 4; ++nt)
                acc[mt][nt] = __builtin_amdgcn_mfma_f32_16x16x32_bf16(af[mt], bfr[nt], acc[mt][nt], 0, 0, 0);
    }
    #pragma unroll
    for (int mt = 0; mt < 2; ++mt)
        #pragma unroll
        for (int nt = 0; nt < 4; ++nt)
            #pragma unroll
            for (int r = 0; r < 4; ++r)
                T[mt * 16 + (l >> 4) * 4 + r][nt * 16 + lm] = (bf16_t)acc[mt][nt][r];
    __syncthreads();
    const int row = l >> 1, ch = (l & 1) * 32;
    bf16_t* dst = out + (size_t)(m0 + row) * 1024 + n0 + ch;
    #pragma unroll
    for (int c = 0; c < 4; ++c) {
        bf16x8 v;
        #pragma unroll
        for (int j = 0; j < 8; ++j) v[j] = T[row][ch + c * 8 + j];
        *(bf16x8*)(dst + c * 8) = v;
    }
}

// conv GEMM: Wc [3][1024][1024] x padded activations xp [2][130][1024], z=4 over i.
__global__ __launch_bounds__(64) void gemm_conv_k(
    const bf16_t* __restrict__ Wc, const bf16_t* __restrict__ xp,
    float* __restrict__ parts)
{
    const int l = threadIdx.x;
    const int n0 = blockIdx.x * 64, m0 = blockIdx.y * 32, i0 = blockIdx.z * 256;
    const int lm = l & 15, lk = (l >> 4) * 8;
    const int b = n0 >> 7, tbase = n0 & 127;
    f32x4 acc[2][4];
    #pragma unroll
    for (int mt = 0; mt < 2; ++mt)
        #pragma unroll
        for (int nt = 0; nt < 4; ++nt) acc[mt][nt] = (f32x4)(0.0f);
    const bf16_t* aq = Wc + (size_t)(m0 + lm) * 1024 + i0 + lk;
    const bf16_t* bq = xp + (size_t)(b * 130 + tbase + lm) * 1024 + i0 + lk;
    #pragma unroll
    for (int r = 0; r < 3; ++r) {
        const bf16_t* ar = aq + (size_t)r * 1048576;
        const bf16_t* br = bq + (size_t)r * 1024;
        for (int kk = 0; kk < 256; kk += 32) {
            bf16x8 af[2], bfr[4];
            #pragma unroll
            for (int i = 0; i < 2; ++i) af[i] = *(const bf16x8*)(ar + (size_t)i * 16384 + kk);
            #pragma unroll
            for (int i = 0; i < 4; ++i) bfr[i] = *(const bf16x8*)(br + (size_t)i * 16384 + kk);
            #pragma unroll
            for (int mt = 0; mt < 2; ++mt)
                #pragma unroll
                for (int nt = 0; nt < 4; ++nt)
                    acc[mt][nt] = __builtin_amdgcn_mfma_f32_16x16x32_bf16(af[mt], bfr[nt], acc[mt][nt], 0, 0, 0);
        }
    }
    float* P = parts + (size_t)blockIdx.z * 262144;
    #pragma unroll
    for (int mt = 0; mt < 2; ++mt) {
        const int row = m0 + mt * 16 + (l >> 4) * 4;
        #pragma unroll
        for (int nt = 0; nt < 4; ++nt) {
            const int col = n0 + nt * 16 + lm;
            #pragma unroll
            for (int r = 0; r < 4; ++r)
                P[(size_t)(row + r) * 256 + col] = acc[mt][nt][r];
        }
    }
}

// reduce conv partials (z=4) -> bias+relu -> bf16 transposed [bt][o] + GN stats
__global__ __launch_bounds__(256) void reduce_convT_k(
    const float* __restrict__ parts, const float* __restrict__ bias,
    bf16_t* __restrict__ out, int rowsPerB, int rowOff,
    float* __restrict__ stats)
{
    __shared__ float T[64][65];
    __shared__ float reds[256], redq[256];
    const int tid = threadIdx.x;
    const int bt0 = blockIdx.x * 64, o0 = blockIdx.y * 64;
    const int b = bt0 >> 7;
    const int ro = tid >> 2, cq = tid & 3;
    float s = 0.f, q = 0.f;
    const float bv = bias[o0 + ro];
    #pragma unroll
    for (int j = 0; j < 4; ++j) {
        const int c4 = cq * 4 + j;
        const float4* src = (const float4*)(parts + (size_t)(o0 + ro) * 256 + bt0) + c4;
        float4 v = src[0];
        #pragma unroll
        for (int z = 1; z < 4; ++z) {
            float4 w = src[z * 65536];
            v.x += w.x; v.y += w.y; v.z += w.z; v.w += w.w;
        }
        v.x = fmaxf(v.x + bv, 0.f); v.y = fmaxf(v.y + bv, 0.f);
        v.z = fmaxf(v.z + bv, 0.f); v.w = fmaxf(v.w + bv, 0.f);
        T[ro][c4 * 4 + 0] = v.x; T[ro][c4 * 4 + 1] = v.y;
        T[ro][c4 * 4 + 2] = v.z; T[ro][c4 * 4 + 3] = v.w;
        s += v.x + v.y + v.z + v.w;
        q += v.x * v.x + v.y * v.y + v.z * v.z + v.w * v.w;
    }
    reds[tid] = s; redq[tid] = q;
    __syncthreads();
    {
        const int rb = tid & 63, og = tid >> 6;
        bf16x8 o8a, o8b;
        #pragma unroll
        for (int j = 0; j < 8; ++j) o8a[j] = (bf16_t)T[og * 16 + j][rb];
        #pragma unroll
        for (int j = 0; j < 8; ++j) o8b[j] = (bf16_t)T[og * 16 + 8 + j][rb];
        const int t = (bt0 & 127) + rb;
        bf16_t* dst = out + (size_t)(b * rowsPerB + rowOff + t) * 1024 + o0 + og * 16;
        *(bf16x8*)dst = o8a;
        *(bf16x8*)(dst + 8) = o8b;
    }
    for (int step = 128; step > 0; step >>= 1) {
        if (tid < step) { reds[tid] += reds[tid + step]; redq[tid] += redq[tid + step]; }
        __syncthreads();
    }
    if (tid == 0) {
        atomicAdd(&stats[b * 2], reds[0]);
        atomicAdd(&stats[b * 2 + 1], redq[0]);
    }
}

// GroupNorm apply in-place on bf16 buffer
__global__ __launch_bounds__(256) void gn_apply_k(
    bf16_t* __restrict__ buf, int rowsPerB, int rowOff,
    const float* __restrict__ stats,
    const float* __restrict__ g, const float* __restrict__ bet)
{
    const int idx4 = blockIdx.x * 256 + threadIdx.x;  // 65536 groups of 4
    const int e = idx4 * 4;
    const int bt = e >> 10, o = e & 1023;
    const int b = bt >> 7, t = bt & 127;
    bf16_t* p = buf + (size_t)(b * rowsPerB + rowOff + t) * 1024 + o;
    const float cnt = 131072.f;
    const float mu = stats[b * 2] / cnt;
    const float var = stats[b * 2 + 1] / cnt - mu * mu;
    const float rs = rsqrtf(var + EPSV);
    bf16x4 v = *(bf16x4*)p;
    float4 gv = *(const float4*)&g[o];
    float4 bv = *(const float4*)&bet[o];
    bf16x4 ov;
    ov[0] = (bf16_t)(((float)v[0] - mu) * rs * gv.x + bv.x);
    ov[1] = (bf16_t)(((float)v[1] - mu) * rs * gv.y + bv.y);
    ov[2] = (bf16_t)(((float)v[2] - mu) * rs * gv.z + bv.z);
    ov[3] = (bf16_t)(((float)v[3] - mu) * rs * gv.w + bv.w);
    *(bf16x4*)p = ov;
}

// durations[bt] = softplus(dot(x2n[bt][:], w3) + b3); one wave per row.
__global__ __launch_bounds__(256) void conv3_k(
    const bf16_t* __restrict__ x, const float* __restrict__ w3,
    const float* __restrict__ b3, float* __restrict__ out)
{
    const int lane = threadIdx.x & 63, w = threadIdx.x >> 6;
    const int bt = blockIdx.x * 4 + w;
    const bf16_t* row = x + (size_t)bt * 1024 + lane * 16;
    bf16x8 v0 = *(const bf16x8*)row;
    bf16x8 v1 = *(const bf16x8*)(row + 8);
    const float* wp = w3 + lane * 16;
    float s = 0.f;
    #pragma unroll
    for (int j = 0; j < 8; ++j) s += (float)v0[j] * wp[j];
    #pragma unroll
    for (int j = 0; j < 8; ++j) s += (float)v1[j] * wp[8 + j];
    #pragma unroll
    for (int off = 32; off > 0; off >>= 1) s += __shfl_down(s, off);
    if (lane == 0) {
        const float t = s + b3[0];
        out[bt] = fmaxf(t, 0.f) + log1pf(expf(-fabsf(t)));
    }
}

// logits partial over h-half: lp[hs][b][a][t] = sum_{h in half} relu(tp+ap)*w2
// block: fixed (a, hs, b), 128 threads = t lanes; ap row half + w2 half in LDS.
__global__ __launch_bounds__(128) void logits_k(
    const bf16_t* __restrict__ tp_bf, const bf16_t* __restrict__ ap_bf,
    const float* __restrict__ w2, float* __restrict__ lp)
{
    __shared__ bf16_t ap_s[512];
    __shared__ float w2_s[512];
    const int a = blockIdx.x, hs = blockIdx.y, b = blockIdx.z;
    const int t = threadIdx.x;
    const bf16_t* aprow = ap_bf + (size_t)(b * 512 + a) * 1024 + hs * 512;
    if (t < 64) *(bf16x8*)&ap_s[t * 8] = *(const bf16x8*)&aprow[t * 8];
    *(float4*)&w2_s[t * 4] = *(const float4*)&w2[hs * 512 + t * 4];
    __syncthreads();
    const bf16_t* tprow = tp_bf + (size_t)(b * 128 + t) * 1024 + hs * 512;
    float acc = 0.f;
    #pragma unroll 4
    for (int h = 0; h < 512; h += 8) {
        bf16x8 tv = *(const bf16x8*)&tprow[h];
        bf16x8 av = *(const bf16x8*)&ap_s[h];
        #pragma unroll
        for (int j = 0; j < 8; ++j)
            acc += fmaxf((float)tv[j] + (float)av[j], 0.f) * w2_s[h + j];
    }
    lp[(size_t)hs * 131072 + (size_t)(b * 512 + a) * 128 + t] = acc;
}

// combine h-halves + bias + monotonic, softmax over a (512) per (b,t) row.
__global__ __launch_bounds__(256) void softmax_k(
    const float* __restrict__ lp, const float* __restrict__ b2,
    float* __restrict__ out)
{
    __shared__ float red[256];
    const int row = blockIdx.x, tid = threadIdx.x;
    const int b = row >> 7, t = row & 127;
    const float b2v = b2[0];
    const float ft4 = 4.0f * (float)t;
    const size_t i0 = (size_t)(b * 512 + tid) * 128 + t;
    const size_t i1 = (size_t)(b * 512 + tid + 256) * 128 + t;
    const float v0 = lp[i0] + lp[131072 + i0] + b2v - 0.1f * fabsf((float)tid - ft4);
    const float v1 = lp[i1] + lp[131072 + i1] + b2v - 0.1f * fabsf((float)(tid + 256) - ft4);
    float m = fmaxf(v0, v1);
    red[tid] = m;
    __syncthreads();
    for (int s = 128; s > 0; s >>= 1) {
        if (tid < s) red[tid] = fmaxf(red[tid], red[tid + s]);
        __syncthreads();
    }
    m = red[0];
    __syncthreads();
    const float e0 = expf(v0 - m), e1 = expf(v1 - m);
    red[tid] = e0 + e1;
    __syncthreads();
    for (int s = 128; s > 0; s >>= 1) {
        if (tid < s) red[tid] += red[tid + s];
        __syncthreads();
    }
    const float inv = 1.0f / red[0];
    out[(size_t)row * 512 + tid] = e0 * inv;
    out[(size_t)row * 512 + tid + 256] = e1 * inv;
}

extern "C" void kernel_launch(void* const* d_in, const int* in_sizes, int n_in,
                              void* d_out, int out_size, void* d_ws, size_t ws_size,
                              hipStream_t stream) {
    const float* text   = (const float*)d_in[0];
    const float* audio  = (const float*)d_in[1];
    const float* a_w1   = (const float*)d_in[2];
    const float* a_b1   = (const float*)d_in[3];
    const float* a_w2   = (const float*)d_in[4];
    const float* a_b2   = (const float*)d_in[5];
    const float* d_w1   = (const float*)d_in[6];
    const float* d_b1   = (const float*)d_in[7];
    const float* gn1_g  = (const float*)d_in[8];
    const float* gn1_b  = (const float*)d_in[9];
    const float* d_w2   = (const float*)d_in[10];
    const float* d_b2   = (const float*)d_in[11];
    const float* gn2_g  = (const float*)d_in[12];
    const float* gn2_b  = (const float*)d_in[13];
    const float* d_w3   = (const float*)d_in[14];
    const float* d_b3   = (const float*)d_in[15];

    char* ws = (char*)d_ws;
    float* outf = (float*)d_out;

    bf16_t* text_bf  = (bf16_t*)(ws + OFF_TEXTBF);
    bf16_t* audio_bf = (bf16_t*)(ws + OFF_AUDIOBF);
    bf16_t* w1topT   = (bf16_t*)(ws + OFF_W1T);
    bf16_t* w1botT   = (bf16_t*)(ws + OFF_W1T + 2097152);
    bf16_t* wc       = (bf16_t*)(ws + OFF_W1T);        // overlays W1T after ap gemm
    bf16_t* tp_bf    = (bf16_t*)(ws + OFF_TPBF);
    bf16_t* ap_bf    = (bf16_t*)(ws + OFF_APBF);
    float*  parts    = (float*) (ws + OFF_PARTS);
    float*  lp       = (float*) (ws + OFF_LP);
    bf16_t* x2n      = (bf16_t*)(ws + OFF_LP);         // overlays lp (earlier in time)
    bf16_t* xp0      = (bf16_t*)(ws + OFF_XP0);
    bf16_t* xp1      = (bf16_t*)(ws + OFF_XP1);
    float*  stats    = (float*) (ws + OFF_STATS);

    // zero xp0 + xp1 pad rows + stats (contiguous region)
    hipMemsetAsync(ws + OFF_XP0, 0, 532480u + 532480u + 32u, stream);

    // prep
    cvt_act_k<<<dim3(1280), 256, 0, stream>>>(text, audio, text_bf, xp0, audio_bf);
    cvt_w1T_k<<<dim3(32, 64), 256, 0, stream>>>(a_w1, w1topT, w1botT);

    // tp = bf16(text @ W1_top + b1)   (split-k z=2)
    gemm_tp_k<<<dim3(16, 8, 2), 64, 0, stream>>>(text_bf, w1topT, parts);
    reduce_tp_k<<<dim3(256), 256, 0, stream>>>(parts, a_b1, tp_bf);

    // ap = bf16(audio @ W1_bot)  [b][a][h], direct epilogue
    gemm_ap_k<<<dim3(16, 32), 64, 0, stream>>>(audio_bf, w1botT, ap_bf);

    // conv1 -> GN1
    cvt_wc_k<<<dim3(1024), 256, 0, stream>>>(d_w1, wc);
    gemm_conv_k<<<dim3(4, 32, 4), 64, 0, stream>>>(wc, xp0, parts);
    reduce_convT_k<<<dim3(4, 16), 256, 0, stream>>>(parts, d_b1, xp1, 130, 1, stats);
    gn_apply_k<<<dim3(256), 256, 0, stream>>>(xp1, 130, 1, stats, gn1_g, gn1_b);

    // conv2 -> GN2
    cvt_wc_k<<<dim3(1024), 256, 0, stream>>>(d_w2, wc);
    gemm_conv_k<<<dim3(4, 32, 4), 64, 0, stream>>>(wc, xp1, parts);
    reduce_convT_k<<<dim3(4, 16), 256, 0, stream>>>(parts, d_b2, x2n, 128, 0, stats + 4);
    gn_apply_k<<<dim3(256), 256, 0, stream>>>(x2n, 128, 0, stats + 4, gn2_g, gn2_b);

    // conv3 + softplus -> durations
    conv3_k<<<dim3(64), 256, 0, stream>>>(x2n, d_w3, d_b3, outf + 131072);

    // logits partials (h-split) + fused combine/softmax -> alignment
    logits_k<<<dim3(512, 2, 2), 128, 0, stream>>>(tp_bf, ap_bf, a_w2, lp);
    softmax_k<<<dim3(256), 256, 0, stream>>>(lp, a_b2, outf);
}